// Round 1
// baseline (125.534 us; speedup 1.0000x reference)
//
#include <hip/hip_runtime.h>

// emb[b,n,i] = cos(pi * i * x[b,n]),  i = 0..127
// rows = b*n = 1,048,576 ; out is row-major [rows][128] f32.
//
// cos(pi*i*x) = cos(2*pi * (i*x/2)) -> v_cos_f32 takes revolutions, so
// value = v_cos(fract(i * x * 0.5)).  fract is an exact period reduction.

constexpr int D = 128;

__global__ __launch_bounds__(256) void Emb_37967510896970_kernel(
    const float* __restrict__ x, float4* __restrict__ out, int total_rows)
{
    const int tx  = threadIdx.x & 31;   // float4 slot within D (32*4 = 128)
    const int ty  = threadIdx.x >> 5;   // row within block (8 rows/block)
    const int rpb = 256 >> 5;           // rows per block = 8
    const float i0 = (float)(tx << 2);  // base i for this thread's float4

    for (int row = blockIdx.x * rpb + ty; row < total_rows;
         row += (int)gridDim.x * rpb) {
        const float h = 0.5f * x[row];  // revolutions per unit i
        float4 v;
        v.x = __builtin_amdgcn_cosf(__builtin_amdgcn_fractf(h * i0));
        v.y = __builtin_amdgcn_cosf(__builtin_amdgcn_fractf(h * (i0 + 1.0f)));
        v.z = __builtin_amdgcn_cosf(__builtin_amdgcn_fractf(h * (i0 + 2.0f)));
        v.w = __builtin_amdgcn_cosf(__builtin_amdgcn_fractf(h * (i0 + 3.0f)));
        out[(size_t)row * (D / 4) + tx] = v;
    }
}

extern "C" void kernel_launch(void* const* d_in, const int* in_sizes, int n_in,
                              void* d_out, int out_size, void* d_ws, size_t ws_size,
                              hipStream_t stream) {
    const float* x = (const float*)d_in[0];
    float4* out = (float4*)d_out;
    const int total_rows = in_sizes[0];          // 256*4096
    const int rpb = 8;                            // rows per 256-thread block
    int grid = (total_rows + rpb - 1) / rpb;
    if (grid > 2048) grid = 2048;                 // grid-stride the rest (G11)
    Emb_37967510896970_kernel<<<grid, 256, 0, stream>>>(x, out, total_rows);
}